// Round 1
// baseline (10.018 us; speedup 1.0000x reference)
//
#include <hip/hip_runtime.h>
#include <float.h>

// SpanMaxPooler: out[b, i*H + h] = valid(b,i) ? max_{s in [start,end)} hidden[b,s,h]
//                                            : missing[i,h]
// B=64, S=512, H=1024, I=2. Spans are 1..32 rows. Tiny, latency-bound kernel.

#define FMAX4(a, v)            \
    a.x = fmaxf(a.x, (v).x);   \
    a.y = fmaxf(a.y, (v).y);   \
    a.z = fmaxf(a.z, (v).z);   \
    a.w = fmaxf(a.w, (v).w);

template <int S, int H, int I, int SPLIT>
__global__ __launch_bounds__(H / SPLIT / 4) void span_max_kernel(
    const float* __restrict__ hidden,   // [B,S,H]
    const int*   __restrict__ start,    // [B,I]
    const int*   __restrict__ end,      // [B,I]
    const float* __restrict__ missing,  // [I,H]
    float*       __restrict__ out)      // [B,I*H]
{
    constexpr int HCHUNK = H / SPLIT;           // columns per block
    const int blk  = blockIdx.x;
    const int part = blk % SPLIT;
    const int span = blk / SPLIT;               // b*I + i
    const int i    = span % I;
    const int h0   = part * HCHUNK + threadIdx.x * 4;

    const int s0 = start[span];
    const int s1 = end[span];

    float4 acc;
    if (s0 < 0 || s1 < 0) {
        // fallback embedding (uniform branch per block)
        acc = *reinterpret_cast<const float4*>(&missing[(size_t)i * H + h0]);
    } else {
        const float* row = hidden + ((size_t)span / I) * (size_t)S * H
                                  + (size_t)s0 * H + h0;
        acc = make_float4(-FLT_MAX, -FLT_MAX, -FLT_MAX, -FLT_MAX);
        const int n = s1 - s0;                  // 1..32
        int s = 0;
        // 4 independent loads in flight per iteration (latency hiding)
        for (; s + 4 <= n; s += 4) {
            float4 v0 = *reinterpret_cast<const float4*>(row + (size_t)(s + 0) * H);
            float4 v1 = *reinterpret_cast<const float4*>(row + (size_t)(s + 1) * H);
            float4 v2 = *reinterpret_cast<const float4*>(row + (size_t)(s + 2) * H);
            float4 v3 = *reinterpret_cast<const float4*>(row + (size_t)(s + 3) * H);
            FMAX4(acc, v0);
            FMAX4(acc, v1);
            FMAX4(acc, v2);
            FMAX4(acc, v3);
        }
        for (; s < n; ++s) {
            float4 v = *reinterpret_cast<const float4*>(row + (size_t)s * H);
            FMAX4(acc, v);
        }
    }

    *reinterpret_cast<float4*>(&out[(size_t)span * H + h0]) = acc;
}

extern "C" void kernel_launch(void* const* d_in, const int* in_sizes, int n_in,
                              void* d_out, int out_size, void* d_ws, size_t ws_size,
                              hipStream_t stream) {
    constexpr int B = 64, S = 512, H = 1024, I = 2;
    constexpr int SPLIT = 2;   // 2 blocks per (b,i) -> 256 blocks total (1/CU)

    const float* hidden  = (const float*)d_in[0];
    const int*   start   = (const int*)d_in[1];
    const int*   end     = (const int*)d_in[2];
    const float* missing = (const float*)d_in[3];
    float*       out     = (float*)d_out;

    const int grid  = B * I * SPLIT;       // 256
    const int block = H / SPLIT / 4;       // 128 threads, float4 each

    span_max_kernel<S, H, I, SPLIT><<<grid, block, 0, stream>>>(
        hidden, start, end, missing, out);
}